// Round 1
// baseline (23.468 us; speedup 1.0000x reference)
//
#include <hip/hip_runtime.h>

// Shapes are fixed by setup_inputs(): b=8, n=512, m=1024, C=16, OUT=1.
#define BB 8
#define NN 512
#define MM 1024
#define CC 16

// One wave (64 lanes) per output element (b,m). Lanes split the n-reduction.
// Per-channel constant mc[c] = -0.5 * exp(-2*sigma_c) * log2(e), so
// w = exp(-0.5*d/scale_c^2) = exp2(d * mc[c])  -> single v_exp_f32.
__global__ __launch_bounds__(256) void final_layer_kernel(
    const float* __restrict__ x,      // (B,N,1)
    const float* __restrict__ y,      // (B,N,C)
    const float* __restrict__ t,      // (B,M,1)
    const float* __restrict__ sigma,  // (C,)
    const float* __restrict__ g_w,    // (1,C)
    const float* __restrict__ g_b,    // (1,)
    float* __restrict__ out)          // (B,M,1)
{
    const int lane = threadIdx.x & 63;
    const int wave = threadIdx.x >> 6;
    const int w    = (blockIdx.x << 2) + wave;   // output index in [0, B*M)
    const int b    = w >> 10;                    // w / M

    const float L2E = 1.44269504088896340736f;

    // Per-channel exponent coefficient (broadcast scalar loads, tiny cost).
    float mc[CC];
#pragma unroll
    for (int c = 0; c < CC; ++c) {
        // exp(-2*sigma) = exp2(-2*sigma*log2e)
        const float k = __builtin_amdgcn_exp2f(-2.0f * L2E * sigma[c]);
        mc[c] = -0.5f * L2E * k;
    }

    const float tv = t[w];   // t[b*M + m] == t[w]

    float acc[CC];
#pragma unroll
    for (int c = 0; c < CC; ++c) acc[c] = 0.0f;

    const float* xb = x + b * NN;
    const float* yb = y + b * NN * CC;

#pragma unroll
    for (int i = 0; i < NN / 64; ++i) {
        const int n   = lane + (i << 6);
        const float dx = xb[n] - tv;
        const float d  = dx * dx;
        const float4* yp = reinterpret_cast<const float4*>(yb + n * CC);
#pragma unroll
        for (int q = 0; q < 4; ++q) {
            const float4 yv = yp[q];
            acc[4*q+0] += yv.x * __builtin_amdgcn_exp2f(d * mc[4*q+0]);
            acc[4*q+1] += yv.y * __builtin_amdgcn_exp2f(d * mc[4*q+1]);
            acc[4*q+2] += yv.z * __builtin_amdgcn_exp2f(d * mc[4*q+2]);
            acc[4*q+3] += yv.w * __builtin_amdgcn_exp2f(d * mc[4*q+3]);
        }
    }

    // Fold channel dot-product with g_w after the n-loop (16 muls total).
    float partial = 0.0f;
#pragma unroll
    for (int c = 0; c < CC; ++c) partial += g_w[c] * acc[c];

    // Wave-level reduce over 64 lanes.
#pragma unroll
    for (int off = 32; off >= 1; off >>= 1)
        partial += __shfl_xor(partial, off, 64);

    if (lane == 0) out[w] = partial + g_b[0];
}

extern "C" void kernel_launch(void* const* d_in, const int* in_sizes, int n_in,
                              void* d_out, int out_size, void* d_ws, size_t ws_size,
                              hipStream_t stream) {
    const float* x     = (const float*)d_in[0];
    const float* y     = (const float*)d_in[1];
    const float* t     = (const float*)d_in[2];
    const float* sigma = (const float*)d_in[3];
    const float* g_w   = (const float*)d_in[4];
    const float* g_b   = (const float*)d_in[5];
    float* out = (float*)d_out;

    // 8192 outputs, 4 waves (one output each) per 256-thread block.
    const int n_out  = BB * MM;
    const int blocks = n_out / 4;
    final_layer_kernel<<<blocks, 256, 0, stream>>>(x, y, t, sigma, g_w, g_b, out);
}

// Round 2
// 14.289 us; speedup vs baseline: 1.6424x; 1.6424x over previous
//
#include <hip/hip_runtime.h>

// Shapes fixed by setup_inputs(): b=8, n=512, m=1024, C=16, OUT=1.
#define BB 8
#define NN 512
#define MM 1024
#define CC 16
#define MG 32      // m-values per block
#define WAVES 8    // 512 threads per block

// One m per lane (lanes 0-31 and 32-63 duplicate the same 32 m's but cover
// disjoint n-chunks). y[b] (32 KB) staged in LDS; inner-loop y reads are
// half-wave-uniform -> LDS broadcast (conflict-free). Inner op per (n,c):
// one v_mul + one v_exp_f32 + one v_fma. Trans-pipe floor ~3.4 us.
__global__ __launch_bounds__(512) void final_layer_kernel(
    const float* __restrict__ x,      // (B,N,1)
    const float* __restrict__ y,      // (B,N,C)
    const float* __restrict__ t,      // (B,M,1)
    const float* __restrict__ sigma,  // (C,)
    const float* __restrict__ g_w,    // (1,C)
    const float* __restrict__ g_b,    // (1,)
    float* __restrict__ out)          // (B,M,1)
{
    __shared__ float y_lds[NN * CC];     // 32 KB
    __shared__ float x_lds[NN];          // 2 KB
    __shared__ float red[WAVES][MG];     // 1 KB

    const int tid  = threadIdx.x;
    const int lane = tid & 63;
    const int wave = tid >> 6;
    const int b    = blockIdx.x >> 5;    // 32 m-groups per batch
    const int mg   = blockIdx.x & 31;

    // ---- stage y[b] and x[b] into LDS (coalesced float4) ----
    const float4* ysrc = reinterpret_cast<const float4*>(y + b * NN * CC);
    float4*       ydst = reinterpret_cast<float4*>(y_lds);
#pragma unroll
    for (int i = 0; i < (NN * CC / 4) / 512; ++i)   // 4 iters
        ydst[tid + i * 512] = ysrc[tid + i * 512];
    x_lds[tid] = x[b * NN + tid];                   // tid < 512 == NN
    if (tid + 0 == tid && NN > 512) { /* unreachable guard */ }

    // ---- per-channel exponent coefficient: mc = -0.5*log2(e)*exp(-2*sigma) ----
    const float L2E = 1.44269504088896340736f;
    float mc[CC];
#pragma unroll
    for (int c = 0; c < CC; ++c)
        mc[c] = -0.5f * L2E * __builtin_amdgcn_exp2f(-2.0f * L2E * sigma[c]);

    const int   mloc = lane & 31;
    const int   half = lane >> 5;
    const float tv   = t[b * MM + mg * MG + mloc];

    float acc[CC];
#pragma unroll
    for (int c = 0; c < CC; ++c) acc[c] = 0.0f;

    __syncthreads();

    // ---- main loop: each (wave, half) owns a 32-wide n-chunk ----
    const int n0 = (wave * 2 + half) * 32;
#pragma unroll 4
    for (int i = 0; i < 32; ++i) {
        const int   n  = n0 + i;
        const float dx = x_lds[n] - tv;
        const float d  = dx * dx;
        const float4* yr = reinterpret_cast<const float4*>(&y_lds[n * CC]);
#pragma unroll
        for (int q = 0; q < 4; ++q) {
            const float4 yv = yr[q];
            acc[4*q+0] += yv.x * __builtin_amdgcn_exp2f(d * mc[4*q+0]);
            acc[4*q+1] += yv.y * __builtin_amdgcn_exp2f(d * mc[4*q+1]);
            acc[4*q+2] += yv.z * __builtin_amdgcn_exp2f(d * mc[4*q+2]);
            acc[4*q+3] += yv.w * __builtin_amdgcn_exp2f(d * mc[4*q+3]);
        }
    }

    // ---- epilogue: fold g_w, reduce halves, reduce waves ----
    float s = 0.0f;
#pragma unroll
    for (int c = 0; c < CC; ++c) s += g_w[c] * acc[c];
    s += __shfl_xor(s, 32, 64);          // combine the two n-halves

    if (lane < MG) red[wave][lane] = s;
    __syncthreads();

    if (tid < MG) {
        float r = 0.0f;
#pragma unroll
        for (int w2 = 0; w2 < WAVES; ++w2) r += red[w2][tid];
        out[b * MM + mg * MG + tid] = r + g_b[0];
    }
}

extern "C" void kernel_launch(void* const* d_in, const int* in_sizes, int n_in,
                              void* d_out, int out_size, void* d_ws, size_t ws_size,
                              hipStream_t stream) {
    const float* x     = (const float*)d_in[0];
    const float* y     = (const float*)d_in[1];
    const float* t     = (const float*)d_in[2];
    const float* sigma = (const float*)d_in[3];
    const float* g_w   = (const float*)d_in[4];
    const float* g_b   = (const float*)d_in[5];
    float* out = (float*)d_out;

    // 256 blocks = 8 b x 32 m-groups; one block per CU.
    final_layer_kernel<<<BB * 32, 512, 0, stream>>>(x, y, t, sigma, g_w, g_b, out);
}

// Round 3
// 9.700 us; speedup vs baseline: 2.4194x; 1.4731x over previous
//
#include <hip/hip_runtime.h>

// Shapes fixed by setup_inputs(): b=8, n=512, m=1024, C=16, OUT=1.
#define BB 8
#define NN 512
#define MM 1024
#define CC 16
#define MG 16      // m-values per block
#define TPB 256    // 4 waves

// LDS pad-swizzle: n -> n + n/32 breaks the 4-distinct-address same-bank
// pattern of the inner ds_read_b64 (reps differ by n=32 -> 256 B -> bank 0).
__device__ __forceinline__ int xzi(int n) { return n + (n >> 5); }

// out[b,m] = sum_n z[b,n] * exp2(mc * (x[b,n]-t[b,m])^2) + g_b   (uniform sigma)
// general fallback: 16 passes, z_c[n] = g_w[c]*y[b,n,c], mc_c per channel.
__global__ __launch_bounds__(TPB) void final_layer_kernel(
    const float* __restrict__ x,      // (B,N,1)
    const float* __restrict__ y,      // (B,N,C)
    const float* __restrict__ t,      // (B,M,1)
    const float* __restrict__ sigma,  // (C,)
    const float* __restrict__ g_w,    // (1,C)
    const float* __restrict__ g_b,    // (1,)
    float* __restrict__ out)          // (B,M,1)
{
    __shared__ float2 xz[NN + NN / 32];   // {x[n], z[n]}, padded
    __shared__ float  red[4][MG];

    const int tid  = threadIdx.x;
    const int lane = tid & 63;
    const int wave = tid >> 6;
    const int b    = blockIdx.x >> 6;     // 64 m-groups per batch
    const int mg   = blockIdx.x & 63;
    const int mloc = tid & 15;
    const int rep  = tid >> 4;            // 16 reps, each owns 32 n-values

    const float L2E = 1.44269504088896340736f;

    // Block-uniform check: all sigma equal?
    const float s0 = sigma[0];
    bool uniform = true;
#pragma unroll
    for (int c = 1; c < CC; ++c) uniform = uniform && (sigma[c] == s0);

    const float tv = t[b * MM + mg * MG + mloc];
    float total = 0.0f;

    if (uniform) {
        const float mc = -0.5f * L2E * __builtin_amdgcn_exp2f(-2.0f * L2E * s0);
        float gw[CC];
#pragma unroll
        for (int c = 0; c < CC; ++c) gw[c] = g_w[c];

        // ---- stage {x, z = y . g_w} for this batch ----
#pragma unroll
        for (int k = 0; k < NN / TPB; ++k) {   // 2 iters
            const int n = tid + k * TPB;
            const float4* yr = reinterpret_cast<const float4*>(y + (size_t)(b * NN + n) * CC);
            float zz = 0.0f;
#pragma unroll
            for (int q = 0; q < 4; ++q) {
                const float4 v = yr[q];
                zz += v.x * gw[4*q+0] + v.y * gw[4*q+1] + v.z * gw[4*q+2] + v.w * gw[4*q+3];
            }
            xz[xzi(n)] = make_float2(x[b * NN + n], zz);
        }
        __syncthreads();

        // ---- main loop: 32 n-values per thread ----
        const int n0 = rep * 32;
#pragma unroll 8
        for (int i = 0; i < 32; ++i) {
            const float2 p = xz[xzi(n0 + i)];
            const float dx = p.x - tv;
            total += p.y * __builtin_amdgcn_exp2f(dx * dx * mc);
        }
    } else {
        // ---- general path: one pass per channel ----
        for (int c = 0; c < CC; ++c) {
            const float mcc = -0.5f * L2E * __builtin_amdgcn_exp2f(-2.0f * L2E * sigma[c]);
            const float gwc = g_w[c];
            __syncthreads();   // protect xz from previous pass's readers
#pragma unroll
            for (int k = 0; k < NN / TPB; ++k) {
                const int n = tid + k * TPB;
                xz[xzi(n)] = make_float2(x[b * NN + n],
                                         gwc * y[(size_t)(b * NN + n) * CC + c]);
            }
            __syncthreads();
            const int n0 = rep * 32;
            float s = 0.0f;
#pragma unroll 8
            for (int i = 0; i < 32; ++i) {
                const float2 p = xz[xzi(n0 + i)];
                const float dx = p.x - tv;
                s += p.y * __builtin_amdgcn_exp2f(dx * dx * mcc);
            }
            total += s;
        }
    }

    // ---- reduce 16 reps per m: 4 in-wave (shfl), then 4 waves via LDS ----
    total += __shfl_xor(total, 16, 64);
    total += __shfl_xor(total, 32, 64);
    if (lane < MG) red[wave][lane] = total;
    __syncthreads();
    if (tid < MG) {
        const float r = red[0][tid] + red[1][tid] + red[2][tid] + red[3][tid];
        out[b * MM + mg * MG + tid] = r + g_b[0];
    }
}

extern "C" void kernel_launch(void* const* d_in, const int* in_sizes, int n_in,
                              void* d_out, int out_size, void* d_ws, size_t ws_size,
                              hipStream_t stream) {
    const float* x     = (const float*)d_in[0];
    const float* y     = (const float*)d_in[1];
    const float* t     = (const float*)d_in[2];
    const float* sigma = (const float*)d_in[3];
    const float* g_w   = (const float*)d_in[4];
    const float* g_b   = (const float*)d_in[5];
    float* out = (float*)d_out;

    // 512 blocks = 8 b x 64 m-groups of 16; 2 blocks/CU.
    final_layer_kernel<<<BB * 64, TPB, 0, stream>>>(x, y, t, sigma, g_w, g_b, out);
}

// Round 4
// 9.624 us; speedup vs baseline: 2.4386x; 1.0080x over previous
//
#include <hip/hip_runtime.h>

// Shapes fixed by setup_inputs(): b=8, n=512, m=1024, C=16, OUT=1.
#define BB 8
#define NN 512
#define MM 1024
#define CC 16
#define MG 8       // m-values per block
#define TPB 256    // 4 waves

// Pad: n -> n + n/16. Inner-loop reads (reps spaced 16 n apart) land in
// banks (16w + 2j + 2i) % 32 -- conflict-free within a wave.
__device__ __forceinline__ int xzi(int n) { return n + (n >> 4); }

// out[b,m] = sum_n z[b,n] * exp2(mc * (x[b,n]-t[b,m])^2) + g_b  (uniform sigma)
// z = y . g_w. General fallback: 16 per-channel passes.
__global__ __launch_bounds__(TPB) void final_layer_kernel(
    const float* __restrict__ x,      // (B,N,1)
    const float* __restrict__ y,      // (B,N,C)
    const float* __restrict__ t,      // (B,M,1)
    const float* __restrict__ sigma,  // (C,)
    const float* __restrict__ g_w,    // (1,C)
    const float* __restrict__ g_b,    // (1,)
    float* __restrict__ out)          // (B,M,1)
{
    __shared__ float2 xz[NN + NN / 16];   // {x[n], z[n]}, padded (4.4 KB)
    __shared__ float  red[4][MG];

    const int tid  = threadIdx.x;
    const int lane = tid & 63;
    const int wave = tid >> 6;
    const int b    = blockIdx.x >> 7;     // 128 m-groups per batch
    const int mg   = blockIdx.x & 127;
    const int mloc = tid & 7;
    const int rep  = tid >> 3;            // 32 reps, each owns 16 n-values

    const float L2E = 1.44269504088896340736f;

    // ---- stage {x, z = y . g_w} immediately (assume uniform sigma);
    //      sigma s_loads overlap these vector loads ----
    float gw[CC];
#pragma unroll
    for (int c = 0; c < CC; ++c) gw[c] = g_w[c];

#pragma unroll
    for (int k = 0; k < NN / TPB; ++k) {   // 2 iters
        const int n = tid + k * TPB;
        const float4* yr = reinterpret_cast<const float4*>(y + (size_t)(b * NN + n) * CC);
        float zz = 0.0f;
#pragma unroll
        for (int q = 0; q < 4; ++q) {
            const float4 v = yr[q];
            zz += v.x * gw[4*q+0] + v.y * gw[4*q+1] + v.z * gw[4*q+2] + v.w * gw[4*q+3];
        }
        xz[xzi(n)] = make_float2(x[b * NN + n], zz);
    }

    const float s0 = sigma[0];
    bool uniform = true;
#pragma unroll
    for (int c = 1; c < CC; ++c) uniform = uniform && (sigma[c] == s0);

    const float tv = t[b * MM + mg * MG + mloc];
    float total = 0.0f;

    __syncthreads();

    if (uniform) {
        const float mc = -0.5f * L2E * __builtin_amdgcn_exp2f(-2.0f * L2E * s0);
        const int n0 = rep * 16;
#pragma unroll
        for (int i = 0; i < 16; ++i) {
            const float2 p = xz[xzi(n0 + i)];
            const float dx = p.x - tv;
            total += p.y * __builtin_amdgcn_exp2f(dx * dx * mc);
        }
    } else {
        // ---- general path: one pass per channel ----
        for (int c = 0; c < CC; ++c) {
            const float mcc = -0.5f * L2E * __builtin_amdgcn_exp2f(-2.0f * L2E * sigma[c]);
            const float gwc = g_w[c];
            __syncthreads();   // previous pass's readers done before overwrite
#pragma unroll
            for (int k = 0; k < NN / TPB; ++k) {
                const int n = tid + k * TPB;
                xz[xzi(n)] = make_float2(x[b * NN + n],
                                         gwc * y[(size_t)(b * NN + n) * CC + c]);
            }
            __syncthreads();
            const int n0 = rep * 16;
            float s = 0.0f;
#pragma unroll
            for (int i = 0; i < 16; ++i) {
                const float2 p = xz[xzi(n0 + i)];
                const float dx = p.x - tv;
                s += p.y * __builtin_amdgcn_exp2f(dx * dx * mcc);
            }
            total += s;
        }
    }

    // ---- reduce 32 reps per m: 8 in-wave (shfl over bits 3..5), 4 waves via LDS ----
    total += __shfl_xor(total, 8, 64);
    total += __shfl_xor(total, 16, 64);
    total += __shfl_xor(total, 32, 64);
    if (lane < MG) red[wave][lane] = total;
    __syncthreads();
    if (tid < MG) {
        const float r = red[0][tid] + red[1][tid] + red[2][tid] + red[3][tid];
        out[b * MM + mg * MG + tid] = r + g_b[0];
    }
}

extern "C" void kernel_launch(void* const* d_in, const int* in_sizes, int n_in,
                              void* d_out, int out_size, void* d_ws, size_t ws_size,
                              hipStream_t stream) {
    const float* x     = (const float*)d_in[0];
    const float* y     = (const float*)d_in[1];
    const float* t     = (const float*)d_in[2];
    const float* sigma = (const float*)d_in[3];
    const float* g_w   = (const float*)d_in[4];
    const float* g_b   = (const float*)d_in[5];
    float* out = (float*)d_out;

    // 1024 blocks = 8 b x 128 m-groups of 8; 4 blocks/CU.
    final_layer_kernel<<<BB * 128, TPB, 0, stream>>>(x, y, t, sigma, g_w, g_b, out);
}